// Round 1
// baseline (1007.932 us; speedup 1.0000x reference)
//
#include <hip/hip_runtime.h>

typedef unsigned short u16;
typedef __attribute__((ext_vector_type(4))) float f32x4;
typedef __attribute__((ext_vector_type(8))) short bf16x8;

__device__ __forceinline__ u16 f2bf(float f) {
  unsigned u = __builtin_bit_cast(unsigned, f);
  u += 0x7FFFu + ((u >> 16) & 1u);   // round-to-nearest-even
  return (u16)(u >> 16);
}

__device__ __forceinline__ void load16(const void* g, void* l) {
  __builtin_amdgcn_global_load_lds((const __attribute__((address_space(1))) void*)g,
                                   (__attribute__((address_space(3))) void*)l, 16, 0, 0);
}

// ---------------- converts ----------------

__global__ void cvt_x(const float* __restrict__ in, u16* __restrict__ out, int n4) {
  int i = blockIdx.x * 256 + threadIdx.x;
  if (i < n4) {
    float4 v = ((const float4*)in)[i];
    ushort4 o;
    o.x = f2bf(v.x); o.y = f2bf(v.y); o.z = f2bf(v.z); o.w = f2bf(v.w);
    ((ushort4*)out)[i] = o;
  }
}

// W[K][N] f32 -> Wt[N][K] bf16
__global__ void cvt_wt(const float* __restrict__ W, u16* __restrict__ Wt, int K, int N) {
  int idx = blockIdx.x * 256 + threadIdx.x;
  if (idx < N * K) {
    int n = idx / K, k = idx - n * K;
    Wt[idx] = f2bf(W[(size_t)k * N + n]);
  }
}

// ---------------- GEMM (A [M][K] bf16, Bt [N][K] bf16) ----------------
// 128x128 tile, BK=32, 4 waves in 2x2, each wave 64x64 (4x4 MFMA 16x16x32)

template <bool BF16OUT>
__global__ __launch_bounds__(256) void gemm_bt(const u16* __restrict__ A,
                                               const u16* __restrict__ Bt,
                                               void* __restrict__ Cout,
                                               const float* __restrict__ bias,
                                               int M, int N, int K) {
  __shared__ __align__(16) u16 lA[128 * 32];
  __shared__ __align__(16) u16 lB[128 * 32];
  const int t = threadIdx.x;
  const int lane = t & 63, wave = t >> 6;
  const int wm = wave & 1, wn = wave >> 1;
  const int col = lane & 15, quad = lane >> 4;
  const int bn = blockIdx.x, bm = blockIdx.y;

  const int rowA = t >> 2;
  const int ke = (t & 3) * 8;
  const u16* gA = A + (size_t)(bm * 128 + rowA) * K + ke;
  const u16* gB = Bt + (size_t)(bn * 128 + rowA) * K + ke;
  u16* dA = &lA[t * 8];
  u16* dB = &lB[t * 8];
  const size_t stride64 = (size_t)64 * K;

  f32x4 acc[4][4] = {};

  for (int k0 = 0; k0 < K; k0 += 32) {
    load16(gA + k0, dA);
    load16(gA + k0 + stride64, dA + 2048);
    load16(gB + k0, dB);
    load16(gB + k0 + stride64, dB + 2048);
    __syncthreads();
    bf16x8 af[4], bfr[4];
#pragma unroll
    for (int i = 0; i < 4; i++)
      af[i] = *(const bf16x8*)&lA[(wm * 64 + i * 16 + col) * 32 + quad * 8];
#pragma unroll
    for (int j = 0; j < 4; j++)
      bfr[j] = *(const bf16x8*)&lB[(wn * 64 + j * 16 + col) * 32 + quad * 8];
#pragma unroll
    for (int i = 0; i < 4; i++)
#pragma unroll
      for (int j = 0; j < 4; j++)
        acc[i][j] = __builtin_amdgcn_mfma_f32_16x16x32_bf16(af[i], bfr[j], acc[i][j], 0, 0, 0);
    __syncthreads();
  }

  const int r0 = bm * 128 + wm * 64 + quad * 4;
  const int c0 = bn * 128 + wn * 64 + col;
  if (BF16OUT) {
    u16* C = (u16*)Cout;
#pragma unroll
    for (int i = 0; i < 4; i++)
#pragma unroll
      for (int j = 0; j < 4; j++)
#pragma unroll
        for (int r = 0; r < 4; r++)
          C[(size_t)(r0 + i * 16 + r) * N + (c0 + j * 16)] = f2bf(acc[i][j][r]);
  } else {
    float* C = (float*)Cout;
    float bv[4];
#pragma unroll
    for (int j = 0; j < 4; j++) bv[j] = bias[c0 + j * 16];
#pragma unroll
    for (int i = 0; i < 4; i++)
#pragma unroll
      for (int j = 0; j < 4; j++)
#pragma unroll
        for (int r = 0; r < 4; r++)
          C[(size_t)(r0 + i * 16 + r) * N + (c0 + j * 16)] = acc[i][j][r] + bv[j];
  }
}

// ---------------- windowed attention ----------------
// grid (12 heads, 36 windows, 8 batch), block 256 (4 waves)
// Q rows padded to 208 (13 m-tiles), keys padded to 224 (14 n-tiles, 7 k-chunks of 32)

#define NQP 208
#define NKP 224
#define QS 72  // padded row stride (elements) for sQ/sK: breaks 128B-stride bank conflict

__global__ __launch_bounds__(256) void win_attn(const u16* __restrict__ qkv,
                                                u16* __restrict__ out) {
  __shared__ __align__(16) u16 sQ[NQP * QS];
  __shared__ __align__(16) u16 sK[NKP * QS];
  __shared__ __align__(16) u16 sVt[64 * NKP];
  __shared__ __align__(16) u16 sP[4][16 * NKP];

  const int h = blockIdx.x;
  const int win = blockIdx.y;
  const int b = blockIdx.z;
  const int wy = win / 6, wx = win - wy * 6;
  const int y0 = wy * 14, x0 = wx * 14;
  const int t = threadIdx.x, wave = t >> 6, lane = t & 63;
  const int col = lane & 15, quad = lane >> 4;

  // ---- stage Q [q][d], K [k][d], V transposed [d][k] ----
  for (int idx = t; idx < (NQP + 2 * NKP) * 8; idx += 256) {
    int part = idx & 7;
    int rowi = idx >> 3;
    int mat, r;
    if (rowi < NQP)            { mat = 0; r = rowi; }
    else if (rowi < NQP + NKP) { mat = 1; r = rowi - NQP; }
    else                       { mat = 2; r = rowi - (NQP + NKP); }
    uint4 val = make_uint4(0u, 0u, 0u, 0u);
    if (r < 196) {
      int iy = r / 14, ix = r - iy * 14;
      int y = y0 + iy, x = x0 + ix;
      if (y < 80 && x < 80) {
        size_t off = ((size_t)(b * 6400 + y * 80 + x)) * 2304 + (size_t)mat * 768 + h * 64 + part * 8;
        val = *(const uint4*)(qkv + off);
      }
    }
    if (mat == 0)      *(uint4*)&sQ[r * QS + part * 8] = val;
    else if (mat == 1) *(uint4*)&sK[r * QS + part * 8] = val;
    else {
      const u16* pv = (const u16*)&val;
#pragma unroll
      for (int j = 0; j < 8; j++) sVt[(part * 8 + j) * NKP + r] = pv[j];
    }
  }
  __syncthreads();

  // ---- per-wave 16-row strips of Q ----
  for (int mt = wave; mt < 13; mt += 4) {
    bf16x8 qa0 = *(const bf16x8*)&sQ[(mt * 16 + col) * QS + quad * 8];
    bf16x8 qa1 = *(const bf16x8*)&sQ[(mt * 16 + col) * QS + 32 + quad * 8];
    f32x4 s[14];
#pragma unroll
    for (int nt = 0; nt < 14; nt++) {
      bf16x8 kb0 = *(const bf16x8*)&sK[(nt * 16 + col) * QS + quad * 8];
      bf16x8 kb1 = *(const bf16x8*)&sK[(nt * 16 + col) * QS + 32 + quad * 8];
      f32x4 a = {0.f, 0.f, 0.f, 0.f};
      a = __builtin_amdgcn_mfma_f32_16x16x32_bf16(qa0, kb0, a, 0, 0, 0);
      a = __builtin_amdgcn_mfma_f32_16x16x32_bf16(qa1, kb1, a, 0, 0, 0);
      s[nt] = a;
    }
    // scale + mask fake key padding (cols >= 196), rowwise max
    float mx[4] = {-1e30f, -1e30f, -1e30f, -1e30f};
#pragma unroll
    for (int nt = 0; nt < 14; nt++)
#pragma unroll
      for (int r = 0; r < 4; r++) {
        float v = s[nt][r] * 0.125f;
        if (nt * 16 + col >= 196) v = -1e30f;
        s[nt][r] = v;
        mx[r] = fmaxf(mx[r], v);
      }
#pragma unroll
    for (int off = 1; off < 16; off <<= 1)
#pragma unroll
      for (int r = 0; r < 4; r++) mx[r] = fmaxf(mx[r], __shfl_xor(mx[r], off));
    float sm[4] = {0.f, 0.f, 0.f, 0.f};
#pragma unroll
    for (int nt = 0; nt < 14; nt++)
#pragma unroll
      for (int r = 0; r < 4; r++) {
        float e = __expf(s[nt][r] - mx[r]);
        s[nt][r] = e;
        sm[r] += e;
      }
#pragma unroll
    for (int off = 1; off < 16; off <<= 1)
#pragma unroll
      for (int r = 0; r < 4; r++) sm[r] += __shfl_xor(sm[r], off);
    float rs[4];
#pragma unroll
    for (int r = 0; r < 4; r++) rs[r] = 1.0f / sm[r];
    // P -> LDS (C-layout -> A-layout round trip)
#pragma unroll
    for (int nt = 0; nt < 14; nt++)
#pragma unroll
      for (int r = 0; r < 4; r++)
        sP[wave][(quad * 4 + r) * NKP + nt * 16 + col] = f2bf(s[nt][r] * rs[r]);
    __threadfence_block();  // order intra-wave LDS write->read
    // O = P V
    f32x4 o[4] = {};
#pragma unroll
    for (int kc = 0; kc < 7; kc++) {
      bf16x8 pa = *(const bf16x8*)&sP[wave][col * NKP + kc * 32 + quad * 8];
#pragma unroll
      for (int dt = 0; dt < 4; dt++) {
        bf16x8 vb = *(const bf16x8*)&sVt[(dt * 16 + col) * NKP + kc * 32 + quad * 8];
        o[dt] = __builtin_amdgcn_mfma_f32_16x16x32_bf16(pa, vb, o[dt], 0, 0, 0);
      }
    }
    // write valid rows
#pragma unroll
    for (int r = 0; r < 4; r++) {
      int qr = mt * 16 + quad * 4 + r;
      if (qr < 196) {
        int iy = qr / 14, ix = qr - iy * 14;
        int y = y0 + iy, x = x0 + ix;
        if (y < 80 && x < 80) {
          size_t off = ((size_t)(b * 6400 + y * 80 + x)) * 768 + h * 64 + col;
#pragma unroll
          for (int dt = 0; dt < 4; dt++) out[off + dt * 16] = f2bf(o[dt][r]);
        }
      }
    }
  }
}

// ---------------- launch ----------------

extern "C" void kernel_launch(void* const* d_in, const int* in_sizes, int n_in,
                              void* d_out, int out_size, void* d_ws, size_t ws_size,
                              hipStream_t stream) {
  const float* x     = (const float*)d_in[0];
  const float* Wqkv  = (const float*)d_in[1];
  const float* Wproj = (const float*)d_in[2];
  const float* bproj = (const float*)d_in[3];

  char* ws = (char*)d_ws;
  const size_t QKV_BYTES = (size_t)51200 * 2304 * 2;  // 235,929,600
  const size_t X_BYTES   = (size_t)51200 * 768 * 2;   //  78,643,200
  const size_t WQT_BYTES = (size_t)2304 * 768 * 2;    //   3,538,944
  u16* qkv    = (u16*)ws;
  u16* xbf    = (u16*)(ws + QKV_BYTES);
  u16* wqkvT  = (u16*)(ws + QKV_BYTES + X_BYTES);
  u16* wprojT = (u16*)(ws + QKV_BYTES + X_BYTES + WQT_BYTES);
  u16* aout   = xbf;  // x dead after GEMM1; attention fully overwrites before GEMM2

  cvt_x<<<38400, 256, 0, stream>>>(x, xbf, 9830400);
  cvt_wt<<<6912, 256, 0, stream>>>(Wqkv, wqkvT, 768, 2304);
  cvt_wt<<<2304, 256, 0, stream>>>(Wproj, wprojT, 768, 768);
  gemm_bt<true><<<dim3(18, 400), 256, 0, stream>>>(xbf, wqkvT, (void*)qkv, nullptr, 51200, 2304, 768);
  win_attn<<<dim3(12, 36, 8), 256, 0, stream>>>(qkv, aout);
  gemm_bt<false><<<dim3(6, 400), 256, 0, stream>>>(aout, wprojT, d_out, bproj, 51200, 768, 768);
}

// Round 2
// 860.582 us; speedup vs baseline: 1.1712x; 1.1712x over previous
//
#include <hip/hip_runtime.h>

typedef unsigned short u16;
typedef __attribute__((ext_vector_type(4))) float f32x4;
typedef __attribute__((ext_vector_type(8))) short bf16x8;

__device__ __forceinline__ u16 f2bf(float f) {
  unsigned u = __builtin_bit_cast(unsigned, f);
  u += 0x7FFFu + ((u >> 16) & 1u);   // round-to-nearest-even
  return (u16)(u >> 16);
}

__device__ __forceinline__ void load16(const void* g, void* l) {
  __builtin_amdgcn_global_load_lds((const __attribute__((address_space(1))) void*)g,
                                   (__attribute__((address_space(3))) void*)l, 16, 0, 0);
}

// wait lgkmcnt(0) only (leave vmcnt alone), plus compiler memory barrier
#define LDS_ORDER() do { __builtin_amdgcn_s_waitcnt(0xC07F); asm volatile("" ::: "memory"); } while (0)

// ---------------- converts ----------------

__global__ void cvt_x(const float* __restrict__ in, u16* __restrict__ out, int n4) {
  int i = blockIdx.x * 256 + threadIdx.x;
  if (i < n4) {
    float4 v = ((const float4*)in)[i];
    ushort4 o;
    o.x = f2bf(v.x); o.y = f2bf(v.y); o.z = f2bf(v.z); o.w = f2bf(v.w);
    ((ushort4*)out)[i] = o;
  }
}

// W[K][N] f32 -> Wt[N][K] bf16
__global__ void cvt_wt(const float* __restrict__ W, u16* __restrict__ Wt, int K, int N) {
  int idx = blockIdx.x * 256 + threadIdx.x;
  if (idx < N * K) {
    int n = idx / K, k = idx - n * K;
    Wt[idx] = f2bf(W[(size_t)k * N + n]);
  }
}

// ---------------- GEMM1: x @ Wqkv, scatter epilogue into windowed layout ----
// qkvP layout: [b][win(36)][mat(3)][h(12)][kidx(196)][d(64)] bf16

__global__ __launch_bounds__(256) void gemm_qkv(const u16* __restrict__ A,
                                                const u16* __restrict__ Bt,
                                                u16* __restrict__ qkvP,
                                                int M, int N, int K) {
  __shared__ __align__(16) u16 lA[128 * 32];
  __shared__ __align__(16) u16 lB[128 * 32];
  const int t = threadIdx.x;
  const int lane = t & 63, wave = t >> 6;
  const int wm = wave & 1, wn = wave >> 1;
  const int col = lane & 15, quad = lane >> 4;
  const int bn = blockIdx.x, bm = blockIdx.y;

  const int rowA = t >> 2;
  const int ke = (t & 3) * 8;
  const u16* gA = A + (size_t)(bm * 128 + rowA) * K + ke;
  const u16* gB = Bt + (size_t)(bn * 128 + rowA) * K + ke;
  u16* dA = &lA[t * 8];
  u16* dB = &lB[t * 8];
  const size_t stride64 = (size_t)64 * K;

  f32x4 acc[4][4] = {};

  for (int k0 = 0; k0 < K; k0 += 32) {
    load16(gA + k0, dA);
    load16(gA + k0 + stride64, dA + 2048);
    load16(gB + k0, dB);
    load16(gB + k0 + stride64, dB + 2048);
    __syncthreads();
    bf16x8 af[4], bfr[4];
#pragma unroll
    for (int i = 0; i < 4; i++)
      af[i] = *(const bf16x8*)&lA[(wm * 64 + i * 16 + col) * 32 + quad * 8];
#pragma unroll
    for (int j = 0; j < 4; j++)
      bfr[j] = *(const bf16x8*)&lB[(wn * 64 + j * 16 + col) * 32 + quad * 8];
#pragma unroll
    for (int i = 0; i < 4; i++)
#pragma unroll
      for (int j = 0; j < 4; j++)
        acc[i][j] = __builtin_amdgcn_mfma_f32_16x16x32_bf16(af[i], bfr[j], acc[i][j], 0, 0, 0);
    __syncthreads();
  }

  // scatter epilogue: col -> (mat,h,d); row -> (b,win,kidx)
  const int c0 = bn * 128 + wn * 64;              // multiple of 64
  const int mat = c0 / 768;                        // uniform per block (768 = 6*128)
  const int hh = (c0 - mat * 768) >> 6;            // uniform per (block, wn)
  const int r0 = bm * 128 + wm * 64 + quad * 4;
#pragma unroll
  for (int i = 0; i < 4; i++) {
#pragma unroll
    for (int r = 0; r < 4; r++) {
      int row = r0 + i * 16 + r;
      int bb = row / 6400;
      int rem = row - bb * 6400;
      int y = rem / 80, x = rem - (rem / 80) * 80;
      int wy = y / 14, wx = x / 14;
      int iy = y - wy * 14, ix = x - wx * 14;
      int win = wy * 6 + wx;
      int kidx = iy * 14 + ix;
      size_t base = ((size_t)((bb * 36 + win) * 3 + mat) * 12 + hh) * 12544 + (size_t)kidx * 64;
#pragma unroll
      for (int j = 0; j < 4; j++)
        qkvP[base + j * 16 + col] = f2bf(acc[i][j][r]);
    }
  }
}

// ---------------- GEMM2: aout @ Wproj + bias -> f32 ----------------

__global__ __launch_bounds__(256) void gemm_proj(const u16* __restrict__ A,
                                                 const u16* __restrict__ Bt,
                                                 float* __restrict__ C,
                                                 const float* __restrict__ bias,
                                                 int M, int N, int K) {
  __shared__ __align__(16) u16 lA[128 * 32];
  __shared__ __align__(16) u16 lB[128 * 32];
  const int t = threadIdx.x;
  const int lane = t & 63, wave = t >> 6;
  const int wm = wave & 1, wn = wave >> 1;
  const int col = lane & 15, quad = lane >> 4;
  const int bn = blockIdx.x, bm = blockIdx.y;

  const int rowA = t >> 2;
  const int ke = (t & 3) * 8;
  const u16* gA = A + (size_t)(bm * 128 + rowA) * K + ke;
  const u16* gB = Bt + (size_t)(bn * 128 + rowA) * K + ke;
  u16* dA = &lA[t * 8];
  u16* dB = &lB[t * 8];
  const size_t stride64 = (size_t)64 * K;

  f32x4 acc[4][4] = {};

  for (int k0 = 0; k0 < K; k0 += 32) {
    load16(gA + k0, dA);
    load16(gA + k0 + stride64, dA + 2048);
    load16(gB + k0, dB);
    load16(gB + k0 + stride64, dB + 2048);
    __syncthreads();
    bf16x8 af[4], bfr[4];
#pragma unroll
    for (int i = 0; i < 4; i++)
      af[i] = *(const bf16x8*)&lA[(wm * 64 + i * 16 + col) * 32 + quad * 8];
#pragma unroll
    for (int j = 0; j < 4; j++)
      bfr[j] = *(const bf16x8*)&lB[(wn * 64 + j * 16 + col) * 32 + quad * 8];
#pragma unroll
    for (int i = 0; i < 4; i++)
#pragma unroll
      for (int j = 0; j < 4; j++)
        acc[i][j] = __builtin_amdgcn_mfma_f32_16x16x32_bf16(af[i], bfr[j], acc[i][j], 0, 0, 0);
    __syncthreads();
  }

  const int r0 = bm * 128 + wm * 64 + quad * 4;
  const int c0 = bn * 128 + wn * 64 + col;
  float bv[4];
#pragma unroll
  for (int j = 0; j < 4; j++) bv[j] = bias[c0 + j * 16];
#pragma unroll
  for (int i = 0; i < 4; i++)
#pragma unroll
    for (int j = 0; j < 4; j++)
#pragma unroll
      for (int r = 0; r < 4; r++)
        C[(size_t)(r0 + i * 16 + r) * N + (c0 + j * 16)] = acc[i][j][r] + bv[j];
}

// ---------------- windowed attention ----------------
// grid (12 heads, 36 windows, 8 batch), block 256 (4 waves)
// LDS: sK [2][208][32] (26624 B) + sVt [7][64][32] (28672 B) + sVrow [200][64] (25600 B)
//  = 80896 B  -> 2 blocks/CU (8 waves/CU)
// sP (per-wave 16x36 + pad, 1280 B) aliases sVrow (dead after transpose).

__global__ __launch_bounds__(256) void win_attn(const u16* __restrict__ qkvP,
                                                u16* __restrict__ out) {
  __shared__ __align__(16) u16 sK[2 * 208 * 32];
  __shared__ __align__(16) u16 sVt[7 * 64 * 32];
  __shared__ __align__(16) u16 sVrow[200 * 64];

  const int h = blockIdx.x;
  const int win = blockIdx.y;
  const int b = blockIdx.z;
  const int wy = win / 6, wx = win - wy * 6;
  const int y0 = wy * 14, x0 = wx * 14;
  const int t = threadIdx.x, wave = t >> 6, lane = t & 63;
  const int colq = lane & 15, quad = lane >> 4;

  const size_t bwin = (size_t)(b * 36 + win) * 3;
  const u16* qbase = qkvP + ((bwin + 0) * 12 + h) * 12544;
  const u16* kbase = qkvP + ((bwin + 1) * 12 + h) * 12544;
  const u16* vbase = qkvP + ((bwin + 2) * 12 + h) * 12544;

  // ---- stage K (half-split) and V (row-major) via linear global_load_lds ----
  // K slots 0..1663 (1664 = 26 waves), V slots 1664..3263 ; 3264 = 51 waves
  for (int s = t; s < 3264; s += 256) {
    if (s < 1664) {
      int half = s / 832;
      int rem = s - half * 832;
      int row = rem >> 2, e = rem & 3;
      int srow = row < 196 ? row : 0;    // clamp: garbage rows masked later
      load16(kbase + srow * 64 + half * 32 + e * 8, (u16*)sK + s * 8);
    } else {
      int s2 = s - 1664;                  // reads up to vbase+12800 elems (pad covers)
      load16(vbase + s2 * 8, sVrow + s2 * 8);
    }
  }
  __syncthreads();   // drains vmcnt (global_load_lds) like m97

  // ---- V transpose with swizzle + zero-masking of invalid keys ----
  const bool boundary = (wx == 5) || (wy == 5);
  for (int jj = t; jj < 14336; jj += 256) {
    int kc = jj >> 11;
    int r2 = jj & 2047;
    int j = r2 >> 6, d = r2 & 63;
    int k = (j + d) & 31;
    int kidx = kc * 32 + k;
    u16 val = 0;
    if (kidx < 196) {
      int iy = kidx / 14, ix = kidx - (kidx / 14) * 14;
      if (y0 + iy < 80 && x0 + ix < 80) val = sVrow[kidx * 64 + d];
    }
    sVt[kc * 2048 + d * 32 + k] = val;
  }
  // zero K rows of invalid (padded) tokens so logits are exactly 0 (ref semantics)
  if (boundary) {
    for (int jj = t; jj < 13312; jj += 256) {
      int row = jj >> 6, d = jj & 63;
      if (row < 196) {
        int iy = row / 14, ix = row - (row / 14) * 14;
        if (y0 + iy >= 80 || x0 + ix >= 80)
          sK[((d >> 5) * 208 + row) * 32 + (d & 31)] = 0;
      }
    }
  }
  __syncthreads();

  u16* sPw = sVrow + wave * 640;   // 16 rows x stride 36 (+pad), aliases dead sVrow

  // ---- per-wave 16-row Q strips ----
  int mt = wave;
  const u16* qp = qbase + (mt * 16 + colq) * 64 + quad * 8;
  bf16x8 qa0 = *(const bf16x8*)qp;
  bf16x8 qa1 = *(const bf16x8*)(qp + 32);
  while (mt < 13) {
    int mtn = mt + 4;
    bf16x8 qn0 = qa0, qn1 = qa1;
    if (mtn < 13) {   // prefetch next strip's Q
      const u16* qp2 = qbase + (mtn * 16 + colq) * 64 + quad * 8;
      qn0 = *(const bf16x8*)qp2;
      qn1 = *(const bf16x8*)(qp2 + 32);
    }

    f32x4 s[13];
#pragma unroll
    for (int nt = 0; nt < 13; nt++) {
      bf16x8 kb0 = *(const bf16x8*)&sK[(nt * 16 + colq) * 32 + quad * 8];
      bf16x8 kb1 = *(const bf16x8*)&sK[((208 + nt * 16 + colq)) * 32 + quad * 8];
      f32x4 a = {0.f, 0.f, 0.f, 0.f};
      a = __builtin_amdgcn_mfma_f32_16x16x32_bf16(qa0, kb0, a, 0, 0, 0);
      a = __builtin_amdgcn_mfma_f32_16x16x32_bf16(qa1, kb1, a, 0, 0, 0);
      s[nt] = a;
    }

    float mx[4] = {-1e30f, -1e30f, -1e30f, -1e30f};
#pragma unroll
    for (int nt = 0; nt < 13; nt++)
#pragma unroll
      for (int r = 0; r < 4; r++) {
        float v = s[nt][r] * 0.125f;
        if (nt == 12 && colq >= 4) v = -1e30f;   // keys >= 196 don't exist
        s[nt][r] = v;
        mx[r] = fmaxf(mx[r], v);
      }
#pragma unroll
    for (int off = 1; off < 16; off <<= 1)
#pragma unroll
      for (int r = 0; r < 4; r++) mx[r] = fmaxf(mx[r], __shfl_xor(mx[r], off));
    float sm[4] = {0.f, 0.f, 0.f, 0.f};
#pragma unroll
    for (int nt = 0; nt < 13; nt++)
#pragma unroll
      for (int r = 0; r < 4; r++) {
        float e = __expf(s[nt][r] - mx[r]);
        s[nt][r] = e;
        sm[r] += e;
      }
#pragma unroll
    for (int off = 1; off < 16; off <<= 1)
#pragma unroll
      for (int r = 0; r < 4; r++) sm[r] += __shfl_xor(sm[r], off);
    float rs[4];
#pragma unroll
    for (int r = 0; r < 4; r++) rs[r] = 1.0f / sm[r];

    // ---- O = P V, chunked over 7 key-chunks of 32; P through tiny LDS buffer ----
    f32x4 o[4] = {};
#pragma unroll
    for (int kc = 0; kc < 7; kc++) {
      const int nt0 = kc * 2, nt1 = kc * 2 + 1;
#pragma unroll
      for (int r = 0; r < 4; r++) {
        sPw[(quad * 4 + r) * 36 + colq] = f2bf(s[nt0][r] * rs[r]);
        sPw[(quad * 4 + r) * 36 + 16 + colq] = (nt1 < 13) ? f2bf(s[nt1][r] * rs[r]) : (u16)0;
      }
      LDS_ORDER();
      bf16x8 pa = *(const bf16x8*)&sPw[colq * 36 + quad * 8];
#pragma unroll
      for (int dt = 0; dt < 4; dt++) {
        bf16x8 vb = *(const bf16x8*)&sVt[(kc * 64 + dt * 16 + colq) * 32 + quad * 8];
        o[dt] = __builtin_amdgcn_mfma_f32_16x16x32_bf16(pa, vb, o[dt], 0, 0, 0);
      }
      LDS_ORDER();   // don't let next kc's writes race ahead of this read
    }

    // ---- write valid rows ----
#pragma unroll
    for (int r = 0; r < 4; r++) {
      int qr = mt * 16 + quad * 4 + r;
      if (qr < 196) {
        int iy = qr / 14, ix = qr - (qr / 14) * 14;
        int y = y0 + iy, x = x0 + ix;
        if (y < 80 && x < 80) {
          size_t off = ((size_t)(b * 6400 + y * 80 + x)) * 768 + h * 64 + colq;
#pragma unroll
          for (int dt = 0; dt < 4; dt++) out[off + dt * 16] = f2bf(o[dt][r]);
        }
      }
    }
    qa0 = qn0; qa1 = qn1;
    mt = mtn;
  }
}

// ---------------- launch ----------------

extern "C" void kernel_launch(void* const* d_in, const int* in_sizes, int n_in,
                              void* d_out, int out_size, void* d_ws, size_t ws_size,
                              hipStream_t stream) {
  const float* x     = (const float*)d_in[0];
  const float* Wqkv  = (const float*)d_in[1];
  const float* Wproj = (const float*)d_in[2];
  const float* bproj = (const float*)d_in[3];

  char* ws = (char*)d_ws;
  const size_t QKVP_BYTES = (size_t)130056192 * 2 + 4096;  // 260,116,480 (incl pad)
  const size_t X_BYTES    = (size_t)51200 * 768 * 2;       //  78,643,200
  const size_t WQT_BYTES  = (size_t)2304 * 768 * 2;        //   3,538,944
  u16* qkvP   = (u16*)ws;
  u16* xbf    = (u16*)(ws + QKVP_BYTES);
  u16* wqkvT  = (u16*)(ws + QKVP_BYTES + X_BYTES);
  u16* wprojT = (u16*)(ws + QKVP_BYTES + X_BYTES + WQT_BYTES);
  u16* aout   = xbf;  // x dead after GEMM1; attention fully overwrites before GEMM2

  cvt_x<<<38400, 256, 0, stream>>>(x, xbf, 9830400);
  cvt_wt<<<6912, 256, 0, stream>>>(Wqkv, wqkvT, 768, 2304);
  cvt_wt<<<2304, 256, 0, stream>>>(Wproj, wprojT, 768, 768);
  gemm_qkv<<<dim3(18, 400), 256, 0, stream>>>(xbf, wqkvT, qkvP, 51200, 2304, 768);
  win_attn<<<dim3(12, 36, 8), 256, 0, stream>>>(qkvP, aout);
  gemm_proj<<<dim3(6, 400), 256, 0, stream>>>(aout, wprojT, (float*)d_out, bproj, 51200, 768, 768);
}